// Round 7
// baseline (788.788 us; speedup 1.0000x reference)
//
#include <hip/hip_runtime.h>
#include <hip/hip_bf16.h>
#include <math.h>

// Problem constants
constexpr int B    = 16;
constexpr int H    = 96;
constexpr int W    = 96;
constexpr int C    = 512;
constexpr int D    = 64;
constexpr int NBH  = 24;          // blocks per side
constexpr int NB   = 576;         // num_block_tot
constexpr int HW   = 9216;
constexpr int TOPK = 16;
constexpr int TK2  = 32;          // 2*TOPK
constexpr int NCAND = 40;         // selection threshold rank (exact fp32 re-rank after)
constexpr int KC   = 384;         // OpenBLAS sgemm k-panel (confirmed by R5 pass)
constexpr int CAP  = 64;          // candidate cap (ties)

// ---------------------------------------------------------------- K0: transpose weights
__global__ void k_transpose(const float* __restrict__ Wk, const float* __restrict__ Wq,
                            float* __restrict__ WkT, float* __restrict__ WqT) {
    int idx = blockIdx.x * 256 + threadIdx.x;   // over C*D
    if (idx < C * D) {
        int c = idx >> 6, d = idx & 63;
        WkT[c * D + d] = Wk[d * C + c];
        WqT[c * D + d] = Wq[d * C + c];
    }
}

// ---------------------------------------------------------------- K1: k-GEMM + block means (fused)
// block: 256 thr = 4 waves; covers 8 rows x 32 cols = 256 px of one image b.
// wave: 64 px x 64 d, lane tile 8px x 8d. NUMERICS FROZEN: per (p,d) fmaf chain
// ascending c, split at KC=384: phase A computes e (chunks 12..15) -> k32 raw;
// phase B computes a (chunks 0..11), final = (a + e) + bk. Mean: sequential
// (dy,dx) sum per spatial 4x4 block then *0.0625f -> emb (exact R5 order).
__global__ __launch_bounds__(256, 3) void k_gemm(
    const float* __restrict__ src, const float* __restrict__ WkT,
    const float* __restrict__ bk,
    float* __restrict__ k32, float* __restrict__ emb) {
    __shared__ float sS[256 * 36];   // 36 KB: [px][36], f4 at (c4*4)^xorv(px)

    int t  = threadIdx.x;
    int bx = blockIdx.x;             // 0..575
    int b  = bx / 36;
    int r  = bx % 36;
    int y0 = (r / 3) * 8;
    int x0 = (r % 3) * 32;

    int lane = t & 63, w = t >> 6;
    int pxg = lane & 7, dg = lane >> 3;
    int pxb = w * 64 + pxg * 8;      // lane's 8 px: pxb..pxb+7
    int xr  = pxg << 2;              // read xor: ((px>>3)&7)<<2, same for i=0..7

    float4 bk0 = *(const float4*)&bk[dg * 8];
    float4 bk1 = *(const float4*)&bk[dg * 8 + 4];

    float acc[8][8];

    // two phases: ph=0 -> chunks 12..15 (e), ph=1 -> chunks 0..11 (a)
    #pragma unroll 1
    for (int ph = 0; ph < 2; ++ph) {
        int c_lo = ph ? 0 : 12, c_hi = ph ? 12 : 16;
        #pragma unroll
        for (int i = 0; i < 8; ++i)
            #pragma unroll
            for (int j = 0; j < 8; ++j) acc[i][j] = 0.f;

        #pragma unroll 1
        for (int chunk = c_lo; chunk < c_hi; ++chunk) {
            __syncthreads();   // previous chunk's readers done
            // stage 256 px x 32 cc
            #pragma unroll
            for (int rr = 0; rr < 8; ++rr) {
                int f4 = rr * 256 + t;
                int px = f4 >> 3, c4 = f4 & 7;
                int py = px >> 5, pxx = px & 31;
                const float4 v = *(const float4*)&src[((size_t)(b * HW) + (y0 + py) * W + x0 + pxx) * C + chunk * 32 + c4 * 4];
                int xo = ((px >> 3) & 7) << 2;
                *(float4*)&sS[px * 36 + ((c4 * 4) ^ xo)] = v;
            }
            __syncthreads();

            // fused block-mean for this chunk's 32 cc (exact sequential (dy,dx) order)
            #pragma unroll
            for (int u = 0; u < 2; ++u) {
                int sx  = t >> 5;          // 0..7
                int ccl = t & 31;
                float sum = 0.f;
                #pragma unroll
                for (int dy = 0; dy < 4; ++dy)
                    #pragma unroll
                    for (int dx = 0; dx < 4; ++dx) {
                        int px = (u * 4 + dy) * 32 + sx * 4 + dx;
                        int xo = ((px >> 3) & 7) << 2;
                        float v = sS[px * 36 + (ccl ^ xo)];
                        sum = (dy == 0 && dx == 0) ? v : sum + v;
                    }
                int n = (y0 / 4 + u) * NBH + (x0 / 4 + sx);
                emb[((size_t)b * NB + n) * C + chunk * 32 + ccl] = sum * 0.0625f;
            }

            // GEMM: 8 cc-quads
            #pragma unroll
            for (int cg = 0; cg < 8; ++cg) {
                float4 s4[8];
                #pragma unroll
                for (int i = 0; i < 8; ++i)
                    s4[i] = *(const float4*)&sS[(pxb + i) * 36 + ((cg * 4) ^ xr)];
                #pragma unroll
                for (int j = 0; j < 4; ++j) {
                    int cc = chunk * 32 + cg * 4 + j;
                    float4 wk0 = *(const float4*)&WkT[cc * D + dg * 8];
                    float4 wk1 = *(const float4*)&WkT[cc * D + dg * 8 + 4];
                    const float* w0 = (const float*)&wk0;
                    const float* w1 = (const float*)&wk1;
                    #pragma unroll
                    for (int i = 0; i < 8; ++i) {
                        float sv = ((const float*)&s4[i])[j];
                        #pragma unroll
                        for (int jj = 0; jj < 4; ++jj) {
                            acc[i][jj]     = __builtin_fmaf(sv, w0[jj], acc[i][jj]);
                            acc[i][jj + 4] = __builtin_fmaf(sv, w1[jj], acc[i][jj + 4]);
                        }
                    }
                }
            }
        }

        // write out: phase A raw e; phase B (a + e) + bk
        #pragma unroll
        for (int i = 0; i < 8; ++i) {
            int px = pxb + i;
            size_t gp = (size_t)b * HW + (y0 + (px >> 5)) * W + x0 + (px & 31);
            float* kp = &k32[gp * D + dg * 8];
            if (ph == 0) {
                float4 o0 = {acc[i][0], acc[i][1], acc[i][2], acc[i][3]};
                float4 o1 = {acc[i][4], acc[i][5], acc[i][6], acc[i][7]};
                *(float4*)kp = o0;
                *(float4*)(kp + 4) = o1;
            } else {
                float4 e0 = *(const float4*)kp;
                float4 e1 = *(const float4*)(kp + 4);
                float4 o0, o1;
                o0.x = (acc[i][0] + e0.x) + ((const float*)&bk0)[0];
                o0.y = (acc[i][1] + e0.y) + ((const float*)&bk0)[1];
                o0.z = (acc[i][2] + e0.z) + ((const float*)&bk0)[2];
                o0.w = (acc[i][3] + e0.w) + ((const float*)&bk0)[3];
                o1.x = (acc[i][4] + e1.x) + ((const float*)&bk1)[0];
                o1.y = (acc[i][5] + e1.y) + ((const float*)&bk1)[1];
                o1.z = (acc[i][6] + e1.z) + ((const float*)&bk1)[2];
                o1.w = (acc[i][7] + e1.w) + ((const float*)&bk1)[3];
                *(float4*)kp = o0;
                *(float4*)(kp + 4) = o1;
            }
        }
    }
}

// ---------------------------------------------------------------- K1b: q from emb (frozen chain)
__global__ __launch_bounds__(256) void k_q(
    const float* __restrict__ emb, const float* __restrict__ WqT,
    const float* __restrict__ bq, float* __restrict__ q32) {
    int t = threadIdx.x;
    int n = blockIdx.x * 4 + (t >> 6);   // global row index b*NB+n
    int d = t & 63;
    const float* er = emb + (size_t)n * C;
    float qa = 0.f;
    for (int cc = 0; cc < KC; ++cc)
        qa = __builtin_fmaf(er[cc], WqT[cc * D + d], qa);
    float qe = 0.f;
    for (int cc = KC; cc < C; ++cc)
        qe = __builtin_fmaf(er[cc], WqT[cc * D + d], qe);
    q32[(size_t)n * D + d] = (qa + qe) + bq[d];
}

// ---------------------------------------------------------------- K2: scores SHADOW (fp16) — numerics free
__global__ __launch_bounds__(256) void k_scores(
    const float* __restrict__ q32, const float* __restrict__ k32,
    _Float16* __restrict__ S16) {
    __shared__ float sQ[32][68];
    __shared__ float sK[32][68];

    int t  = threadIdx.x;
    int p0 = blockIdx.x * 32;      // 288 tiles
    int n0 = blockIdx.y * 32;      // 18 tiles
    int b  = blockIdx.z;
    int tx = t & 15, ty = t >> 4;

    const float* qb = q32 + ((size_t)b * NB + n0) * D;
    const float* kb = k32 + ((size_t)b * HW + p0) * D;

    #pragma unroll
    for (int r = 0; r < 2; ++r) {
        int f4 = r * 256 + t;
        int row = f4 >> 4, c4 = f4 & 15;
        *(float4*)&sQ[row][c4 * 4] = *(const float4*)&qb[(size_t)row * D + c4 * 4];
        *(float4*)&sK[row][c4 * 4] = *(const float4*)&kb[(size_t)row * D + c4 * 4];
    }
    __syncthreads();

    int nr = 2 * ty, pc = 2 * tx;
    float acc[2][2] = {};
    for (int d0 = 0; d0 < 16; ++d0) {
        float4 qa = *(const float4*)&sQ[nr][d0 * 4];
        float4 qc = *(const float4*)&sQ[nr + 1][d0 * 4];
        float4 ka = *(const float4*)&sK[pc][d0 * 4];
        float4 kc = *(const float4*)&sK[pc + 1][d0 * 4];
        const float* qaf = (const float*)&qa;
        const float* qcf = (const float*)&qc;
        const float* kaf = (const float*)&ka;
        const float* kcf = (const float*)&kc;
        #pragma unroll
        for (int l = 0; l < 4; ++l) {
            acc[0][0] = __builtin_fmaf(qaf[l], kaf[l], acc[0][0]);
            acc[0][1] = __builtin_fmaf(qaf[l], kcf[l], acc[0][1]);
            acc[1][0] = __builtin_fmaf(qcf[l], kaf[l], acc[1][0]);
            acc[1][1] = __builtin_fmaf(qcf[l], kcf[l], acc[1][1]);
        }
    }
    _Float16* Sb = S16 + (size_t)b * NB * HW;
    #pragma unroll
    for (int oy = 0; oy < 2; ++oy) {
        _Float16 h0 = (_Float16)acc[oy][0];
        _Float16 h1 = (_Float16)acc[oy][1];
        unsigned int pack = ((unsigned int)*(unsigned short*)&h1 << 16) |
                            (unsigned int)*(unsigned short*)&h0;
        *(unsigned int*)&Sb[(size_t)(n0 + nr + oy) * HW + (p0 + pc)] = pack;
    }
}

// ---------------------------------------------------------------- K3: per-row top-k via 2-pass radix select
__global__ __launch_bounds__(256) void k_topk(
    const _Float16* __restrict__ S16,
    const float* __restrict__ q32, const float* __restrict__ k32,
    int* __restrict__ cidx, float* __restrict__ cval, double* __restrict__ rowss) {
    __shared__ int    hist[4][256];   // per-wave sub-histograms
    __shared__ int    sfx[256];
    __shared__ int    b0s, mAbove, thrS, gcnt;
    __shared__ int    cps[CAP];
    __shared__ float  cv[CAP];
    __shared__ int    cp[CAP];
    __shared__ float  sv[CAP];
    __shared__ int    sp[CAP];
    __shared__ double ssq[TOPK];

    int t   = threadIdx.x;
    int row = blockIdx.x;            // b*NB + n
    int b = row / NB, n = row % NB;
    int wid = t >> 6;

    #pragma unroll
    for (int w = 0; w < 4; ++w) hist[w][t] = 0;
    if (t == 0) gcnt = 0;
    __syncthreads();

    const unsigned short* Srow = (const unsigned short*)(S16 + (size_t)row * HW);
    unsigned int my[36];
    #pragma unroll
    for (int c = 0; c < 9; ++c) {
        ushort4 v4 = ((const ushort4*)Srow)[c * 256 + t];
        #pragma unroll
        for (int j = 0; j < 4; ++j) {
            unsigned int h = (j == 0 ? v4.x : j == 1 ? v4.y : j == 2 ? v4.z : v4.w);
            unsigned int m = (h & 0x8000u) ? (h ^ 0xFFFFu) : (h | 0x8000u);
            int p = (c * 256 + t) * 4 + j;
            int hh = p / W, ww = p - hh * W;
            if (((hh >> 2) * NBH + (ww >> 2)) == n) m = 0;   // self-block mask
            my[c * 4 + j] = m;
            atomicAdd(&hist[wid][m >> 8], 1);
        }
    }
    __syncthreads();

    sfx[t] = hist[0][t] + hist[1][t] + hist[2][t] + hist[3][t];
    __syncthreads();
    #pragma unroll
    for (int off = 1; off < 256; off <<= 1) {
        int v = (t + off < 256) ? sfx[t + off] : 0;
        __syncthreads();
        sfx[t] += v;
        __syncthreads();
    }
    if (sfx[t] >= NCAND && (t == 255 || sfx[t + 1] < NCAND)) {
        b0s = t; mAbove = (t == 255) ? 0 : sfx[t + 1];
    }
    __syncthreads();
    int b0 = b0s, mab = mAbove;
    __syncthreads();

    #pragma unroll
    for (int w = 0; w < 4; ++w) hist[w][t] = 0;
    __syncthreads();
    #pragma unroll
    for (int i = 0; i < 36; ++i)
        if ((int)(my[i] >> 8) == b0) atomicAdd(&hist[wid][my[i] & 255u], 1);
    __syncthreads();
    sfx[t] = hist[0][t] + hist[1][t] + hist[2][t] + hist[3][t];
    __syncthreads();
    #pragma unroll
    for (int off = 1; off < 256; off <<= 1) {
        int v = (t + off < 256) ? sfx[t + off] : 0;
        __syncthreads();
        sfx[t] += v;
        __syncthreads();
    }
    if (mab + sfx[t] >= NCAND && (t == 255 || mab + sfx[t + 1] < NCAND))
        thrS = (b0 << 8) | t;
    __syncthreads();
    unsigned int thr = (unsigned int)thrS;

    #pragma unroll
    for (int i = 0; i < 36; ++i) {
        if (my[i] >= thr) {
            int pos = atomicAdd(&gcnt, 1);
            if (pos < CAP) {
                int c = i >> 2, j = i & 3;
                cps[pos] = (c * 256 + t) * 4 + j;
            }
        }
    }
    __syncthreads();
    int M = min(gcnt, CAP);

    // exact fp32 re-rank — np.einsum SSE order, no FMA (NUMERICS FROZEN)
    if (t < M) {
        #pragma clang fp contract(off)
        int p = cps[t];
        const float* qr = q32 + (size_t)row * D;
        const float* kr = k32 + ((size_t)b * HW + p) * D;
        float L0 = 0.f, L1 = 0.f, L2 = 0.f, L3 = 0.f;
        #pragma unroll
        for (int j = 0; j < 16; ++j) {
            L0 = L0 + qr[4 * j + 0] * kr[4 * j + 0];
            L1 = L1 + qr[4 * j + 1] * kr[4 * j + 1];
            L2 = L2 + qr[4 * j + 2] * kr[4 * j + 2];
            L3 = L3 + qr[4 * j + 3] * kr[4 * j + 3];
        }
        cv[t] = (L0 + L1) + (L2 + L3);
        cp[t] = p;
    }
    __syncthreads();

    if (t < M) {
        float v = cv[t]; int p = cp[t];
        int rank = 0;
        for (int j = 0; j < M; ++j) {
            float vj = cv[j];
            rank += (vj > v) || (vj == v && cp[j] < p);
        }
        sv[rank] = v; sp[rank] = p;
    }
    __syncthreads();

    if (t < TK2) {
        cval[(size_t)row * TK2 + t] = sv[t];
        cidx[(size_t)row * TK2 + t] = sp[t];
    }
    if (t < TOPK) {
        double vi = (double)sv[t], s = 0.0;
        #pragma unroll
        for (int j = 0; j < TK2; ++j) { double dd = vi - (double)sv[j]; s += dd * dd; }
        ssq[t] = s;
    }
    __syncthreads();
    if (t == 0) {
        double s = 0.0;
        #pragma unroll
        for (int i = 0; i < TOPK; ++i) s += ssq[i];
        rowss[row] = s;
    }
}

// ---------------------------------------------------------------- K4: per-batch RMS -> scale
__global__ void k_rms(const double* __restrict__ rowss, double* __restrict__ scale) {
    __shared__ double sb[256];
    int b = blockIdx.x, t = threadIdx.x;
    double s = 0.0;
    for (int r = t; r < NB; r += 256) s += rowss[b * NB + r];
    sb[t] = s; __syncthreads();
    for (int st = 128; st > 0; st >>= 1) {
        if (t < st) sb[t] += sb[t + st];
        __syncthreads();
    }
    if (t == 0) {
        double rms = sqrt(sb[0] / ((double)NB * TOPK * TK2));
        scale[b] = 10.0 / (rms + 1e-3);
    }
}

// ---------------------------------------------------------------- K5: finalize — SOLE writer of d_out (float32)
__global__ __launch_bounds__(256) void k_final(
    const int* __restrict__ cidx, const float* __restrict__ cval,
    const double* __restrict__ scale, float* __restrict__ out) {
    __shared__ double sv[16][TK2];
    int t = threadIdx.x;
    int row0 = blockIdx.x * 16;
    for (int idx = t; idx < 16 * TK2; idx += 256) {
        int r = idx >> 5, j = idx & 31;
        sv[r][j] = (double)cval[(size_t)(row0 + r) * TK2 + j];
    }
    __syncthreads();
    int r = t >> 4, i = t & 15;
    int row = row0 + r;
    double scb = scale[row / NB];
    double vi = sv[r][i];
    double s = 0.0;
    #pragma unroll
    for (int j = 0; j < TK2; ++j) {
        double x = (vi - sv[r][j]) * scb;
        s += 1.0 / (1.0 + exp(-x));
    }
    out[(size_t)B * NB * TOPK + (size_t)row * TOPK + i] = (float)tanh(s - (double)TOPK);
    out[(size_t)row * TOPK + i] = (float)cidx[(size_t)row * TK2 + i];
}

// ---------------------------------------------------------------- sentinel fill (ws too small)
__global__ void k_fill(float* out, int nelem) {
    int i = blockIdx.x * 256 + threadIdx.x;
    if (i < nelem) out[i] = -12345.0f;
}

// ---------------------------------------------------------------- launch
extern "C" void kernel_launch(void* const* d_in, const int* in_sizes, int n_in,
                              void* d_out, int out_size, void* d_ws, size_t ws_size,
                              hipStream_t stream) {
    const float* src = (const float*)d_in[0];
    const float* Wq  = (const float*)d_in[1];
    const float* bq  = (const float*)d_in[2];
    const float* Wk  = (const float*)d_in[3];
    const float* bk  = (const float*)d_in[4];
    float* out = (float*)d_out;

    char* ws = (char*)d_ws;
    size_t oWkT = 0;
    size_t oWqT = oWkT + (size_t)C * D * 4;
    size_t oQ   = oWqT + (size_t)C * D * 4;
    size_t oK   = oQ   + (size_t)B * NB * D * 4;
    size_t oS   = oK   + (size_t)B * HW * D * 4;
    size_t oEmb = oS   + (size_t)B * NB * HW * 2;
    size_t oCV  = oEmb + (size_t)B * NB * C * 4;
    size_t oCI  = oCV  + (size_t)B * NB * TK2 * 4;
    size_t oRS  = oCI  + (size_t)B * NB * TK2 * 4;
    size_t oSc  = oRS  + (size_t)B * NB * 8;
    size_t need = oSc  + (size_t)B * 8;

    if (ws_size < need) {
        k_fill<<<(out_size + 255) / 256, 256, 0, stream>>>(out, out_size);
        return;
    }

    float*     WkT  = (float*)(ws + oWkT);
    float*     WqT  = (float*)(ws + oWqT);
    float*     q32  = (float*)(ws + oQ);
    float*     k32  = (float*)(ws + oK);
    _Float16*  S16  = (_Float16*)(ws + oS);
    float*     emb  = (float*)(ws + oEmb);
    float*     cval = (float*)(ws + oCV);
    int*       cidx = (int*)(ws + oCI);
    double*    rss  = (double*)(ws + oRS);
    double*    scl  = (double*)(ws + oSc);

    k_transpose<<<(C * D + 255) / 256, 256, 0, stream>>>(Wk, Wq, WkT, WqT);
    k_gemm<<<576, 256, 0, stream>>>(src, WkT, bk, k32, emb);
    k_q<<<B * NB / 4, 256, 0, stream>>>(emb, WqT, bq, q32);
    k_scores<<<dim3(HW / 32, NB / 32, B), 256, 0, stream>>>(q32, k32, S16);
    k_topk<<<B * NB, 256, 0, stream>>>(S16, q32, k32, cidx, cval, rss);
    k_rms<<<B, 256, 0, stream>>>(rss, scl);
    k_final<<<B * NB / 16, 256, 0, stream>>>(cidx, cval, scl, out);
}